// Round 1
// baseline (304.138 us; speedup 1.0000x reference)
//
#include <hip/hip_runtime.h>

// DynamicConv2d: B=16, CIN=COUT=64, K=3, H=W=192, OH=OW=190, DEG=64, HID=256
// out[b][co][oy][ox] = sum_{ci,ky,kx} w[b][co][ci][ky][kx] * x[b][ci][oy+ky][ox+kx]
// w = (relu(deg@W1+b1)@W2+b2).reshape(B,COUT,CIN,3,3)

typedef __bf16 bf16x8 __attribute__((ext_vector_type(8)));
typedef float  f32x4  __attribute__((ext_vector_type(4)));

#define NB   16
#define CIN  64
#define COUT 64
#define HW   192
#define OHW  190
#define NPIX (HW*HW)        // 36864
#define NW2  (COUT*CIN*9)   // 36864

__device__ __forceinline__ unsigned short f2bf(float f) {
    union { float f; unsigned int u; } v; v.f = f;
    unsigned int r = v.u + 0x7FFFu + ((v.u >> 16) & 1u);   // RNE
    return (unsigned short)(r >> 16);
}
__device__ __forceinline__ float bf2f(unsigned short s) {
    union { unsigned int u; float f; } v; v.u = ((unsigned int)s) << 16;
    return v.f;
}

// ---------------- k1: h = relu(deg @ W1 + b1)  [16,256] ----------------
__global__ void k1_hidden(const float* __restrict__ deg, const float* __restrict__ W1,
                          const float* __restrict__ b1, float* __restrict__ h) {
    int b = blockIdx.x, j = threadIdx.x;
    float acc = b1[j];
    for (int d = 0; d < 64; ++d) acc += deg[b*64 + d] * W1[d*256 + j];
    h[b*256 + j] = fmaxf(acc, 0.f);
}

// ---------------- k2: weights = h @ W2 + b2 -> Aw[b][tap][co][ci] bf16 ----------------
__global__ void k2_wgen(const float* __restrict__ h, const float* __restrict__ W2,
                        const float* __restrict__ b2, unsigned short* __restrict__ Aw) {
    __shared__ float hs[16*256];
    int t = threadIdx.x;
    for (int i = t; i < 16*256; i += 256) hs[i] = h[i];
    __syncthreads();
    int n = blockIdx.x * 256 + t;            // 144 blocks * 256 = 36864 exact
    float acc[16];
    float bias = b2[n];
    for (int b = 0; b < 16; ++b) acc[b] = bias;
    for (int k = 0; k < 256; ++k) {
        float w = W2[k*NW2 + n];
        #pragma unroll
        for (int b = 0; b < 16; ++b) acc[b] += hs[b*256 + k] * w;
    }
    // n = co*576 + ci*9 + tap   (reshape order COUT,CIN,3,3)
    int co  = n / 576;
    int rem = n - co*576;
    int ci  = rem / 9;
    int tap = rem - ci*9;
    for (int b = 0; b < 16; ++b)
        Aw[(((b*9 + tap)*COUT + co)*CIN) + ci] = f2bf(acc[b]);
}

// ---------------- k3: xT[b][p][ci] bf16 = x[b][ci][p] ----------------
__global__ void k3_transpose(const float* __restrict__ x, unsigned short* __restrict__ xT) {
    __shared__ float tile[64][65];
    int b  = blockIdx.y;
    int p0 = blockIdx.x * 64;
    int t  = threadIdx.x;
    const float* xb = x + (size_t)b * CIN * NPIX;
    {
        int c  = t & 63;     // p within tile
        int r0 = t >> 6;     // 0..3
        #pragma unroll
        for (int i = 0; i < 16; ++i) {
            int ci = r0 + i*4;
            tile[ci][c] = xb[ci*NPIX + p0 + c];
        }
    }
    __syncthreads();
    {
        int ci2 = (t & 31) * 2;
        int pr0 = t >> 5;    // 0..7
        #pragma unroll
        for (int i = 0; i < 8; ++i) {
            int pl = pr0 + i*8;
            unsigned int v = (unsigned int)f2bf(tile[ci2][pl])
                           | ((unsigned int)f2bf(tile[ci2+1][pl]) << 16);
            *(unsigned int*)(&xT[((size_t)b*NPIX + p0 + pl)*CIN + ci2]) = v;
        }
    }
}

// ---------------- k4: MFMA conv ----------------
// grid (6,24,16); block 256 (4 waves). Tile: 64co x (8y x 32x).
// LDS xs: [gyl 0..9][gxl 0..33][ci 0..63] bf16, ci stored as 8 chunks of 16B,
// chunk XOR-swizzled by (gx&7) to kill bank conflicts on B-frag reads.
__global__ __launch_bounds__(256, 2)
void k4_conv(const unsigned short* __restrict__ xT, const unsigned short* __restrict__ Aw,
             float* __restrict__ out) {
    __shared__ unsigned short xs[10*34*64];   // 43520 B
    const int b  = blockIdx.z;
    const int x0 = blockIdx.x * 32;
    const int y0 = blockIdx.y * 8;
    const int tid = threadIdx.x;

    // ---- stage input tile (bf16 channels-last, swizzled chunks) ----
    const unsigned short* xTb = xT + (size_t)b * NPIX * CIN;
    for (int q = tid; q < 10*34*8; q += 256) {
        int c   = q & 7;
        int t   = q >> 3;
        int gxl = t % 34;
        int gyl = t / 34;
        int gy = y0 + gyl; if (gy > 191) gy = 191;
        int gx = x0 + gxl; if (gx > 191) gx = 191;
        uint4 v = *(const uint4*)(xTb + ((gy*HW + gx)*CIN + c*8));
        int swc = c ^ (gx & 7);
        *(uint4*)(&xs[(t*8 + swc)*8]) = v;
    }
    __syncthreads();

    const int wv  = tid >> 6;    // wave 0..3 -> rows 2w,2w+1
    const int l   = tid & 63;
    const int l15 = l & 15;
    const int lg  = l >> 4;      // 0..3

    f32x4 acc[4][4] = {};        // [m co-group][n = r*2+xb]

    const unsigned short* Ab = Aw + b * (9*COUT*CIN);
    for (int tap = 0; tap < 9; ++tap) {
        const int ky = tap / 3, kx = tap - 3*(tap/3);
        #pragma unroll
        for (int cc = 0; cc < 2; ++cc) {
            bf16x8 a[4], bb[4];
            #pragma unroll
            for (int m = 0; m < 4; ++m)
                a[m] = *(const bf16x8*)(Ab + (tap*COUT + m*16 + l15)*CIN + cc*32 + lg*8);
            #pragma unroll
            for (int r = 0; r < 2; ++r)
                #pragma unroll
                for (int xb = 0; xb < 2; ++xb) {
                    int gyl = 2*wv + r + ky;
                    int gxl = xb*16 + l15 + kx;
                    int pch = (cc*4 + lg) ^ (gxl & 7);
                    bb[r*2 + xb] = *(const bf16x8*)(&xs[((gyl*34 + gxl)*8 + pch)*8]);
                }
            #pragma unroll
            for (int m = 0; m < 4; ++m)
                #pragma unroll
                for (int n = 0; n < 4; ++n)
                    acc[m][n] = __builtin_amdgcn_mfma_f32_16x16x32_bf16(a[m], bb[n], acc[m][n], 0, 0, 0);
        }
    }

    // ---- epilogue: D col = lane&15 (spatial), row = (lane>>4)*4+j (co) ----
    #pragma unroll
    for (int m = 0; m < 4; ++m)
        #pragma unroll
        for (int r = 0; r < 2; ++r)
            #pragma unroll
            for (int xb = 0; xb < 2; ++xb) {
                int oy = y0 + 2*wv + r;
                int ox = x0 + xb*16 + l15;
                if (oy < OHW && ox < OHW) {
                    f32x4 v = acc[m][r*2 + xb];
                    #pragma unroll
                    for (int j = 0; j < 4; ++j) {
                        int co = m*16 + lg*4 + j;
                        out[(((b*COUT + co)*OHW + oy)*OHW) + ox] = v[j];
                    }
                }
            }
}

// ---------------- fallback: naive direct conv (if ws too small for xT) ----------------
__global__ void k4_naive(const float* __restrict__ x, const unsigned short* __restrict__ Aw,
                         float* __restrict__ out) {
    int p = blockIdx.x * 256 + threadIdx.x;
    if (p >= OHW*OHW) return;
    int b = blockIdx.z, co = blockIdx.y;
    int oy = p / OHW, ox = p - oy*OHW;
    const float* xb = x + (size_t)b * CIN * NPIX;
    float acc = 0.f;
    for (int ci = 0; ci < CIN; ++ci)
        for (int ky = 0; ky < 3; ++ky) {
            const float* row = xb + ci*NPIX + (oy + ky)*HW + ox;
            #pragma unroll
            for (int kx = 0; kx < 3; ++kx) {
                float w = bf2f(Aw[(((b*9 + ky*3 + kx)*COUT + co)*CIN) + ci]);
                acc += row[kx] * w;
            }
        }
    out[(((b*COUT + co)*OHW + oy)*OHW) + ox] = acc;
}

extern "C" void kernel_launch(void* const* d_in, const int* in_sizes, int n_in,
                              void* d_out, int out_size, void* d_ws, size_t ws_size,
                              hipStream_t stream) {
    const float* x   = (const float*)d_in[0];
    const float* deg = (const float*)d_in[1];
    const float* W1  = (const float*)d_in[2];
    const float* b1  = (const float*)d_in[3];
    const float* W2  = (const float*)d_in[4];
    const float* b2  = (const float*)d_in[5];
    float* out = (float*)d_out;

    const size_t off_h  = 0;                       // 16 KB
    const size_t off_Aw = 16 * 1024;               // 1.18 MB
    const size_t off_xT = off_Aw + (size_t)NB*9*COUT*CIN*2;   // 1,196,032 (16B aligned)
    const size_t need   = off_xT + (size_t)NB*NPIX*CIN*2;     // ~76.7 MB

    float* h           = (float*)((char*)d_ws + off_h);
    unsigned short* Aw = (unsigned short*)((char*)d_ws + off_Aw);

    k1_hidden<<<16, 256, 0, stream>>>(deg, W1, b1, h);
    k2_wgen<<<NW2/256, 256, 0, stream>>>(h, W2, b2, Aw);

    if (ws_size >= need) {
        unsigned short* xT = (unsigned short*)((char*)d_ws + off_xT);
        k3_transpose<<<dim3(NPIX/64, NB), 256, 0, stream>>>(x, xT);
        k4_conv<<<dim3(6, 24, NB), 256, 0, stream>>>(xT, Aw, out);
    } else {
        k4_naive<<<dim3((OHW*OHW + 255)/256, COUT, NB), 256, 0, stream>>>(x, Aw, out);
    }
}

// Round 2
// 180.374 us; speedup vs baseline: 1.6862x; 1.6862x over previous
//
#include <hip/hip_runtime.h>

// DynamicConv2d: B=16, CIN=COUT=64, K=3, H=W=192, OH=OW=190, DEG=64, HID=256
// out[b][co][oy][ox] = sum_{ci,ky,kx} w[b][co][ci][ky][kx] * x[b][ci][oy+ky][ox+kx]
// w = (relu(deg@W1+b1)@W2+b2).reshape(B,COUT,CIN,3,3)

typedef __bf16 bf16x8 __attribute__((ext_vector_type(8)));
typedef float  f32x4  __attribute__((ext_vector_type(4)));

#define NB   16
#define CIN  64
#define COUT 64
#define HW   192
#define OHW  190
#define NPIX (HW*HW)        // 36864
#define NW2  (COUT*CIN*9)   // 36864

__device__ __forceinline__ unsigned short f2bf(float f) {
    union { float f; unsigned int u; } v; v.f = f;
    unsigned int r = v.u + 0x7FFFu + ((v.u >> 16) & 1u);   // RNE
    return (unsigned short)(r >> 16);
}
__device__ __forceinline__ float bf2f(unsigned short s) {
    union { unsigned int u; float f; } v; v.u = ((unsigned int)s) << 16;
    return v.f;
}

// async global->LDS, 16B per lane. LDS dest: wave-uniform base + lane*16.
__device__ __forceinline__ void async_copy16(const void* gsrc, void* ldst) {
    __builtin_amdgcn_global_load_lds(
        (const __attribute__((address_space(1))) unsigned int*)gsrc,
        (__attribute__((address_space(3))) unsigned int*)ldst, 16, 0, 0);
}

// ---------------- k1: h = relu(deg @ W1 + b1)  [16,256] ----------------
__global__ void k1_hidden(const float* __restrict__ deg, const float* __restrict__ W1,
                          const float* __restrict__ b1, float* __restrict__ h) {
    int b = blockIdx.x, j = threadIdx.x;
    float acc = b1[j];
    for (int d = 0; d < 64; ++d) acc += deg[b*64 + d] * W1[d*256 + j];
    h[b*256 + j] = fmaxf(acc, 0.f);
}

// ---------------- k2: weights = h @ W2 + b2 -> Aw[b][tap][co][ci] bf16 ----------------
// grid 576, block 256. Each block: 64 n-values x full K via 4 k-chunks + LDS reduce.
__global__ void k2_wgen(const float* __restrict__ h, const float* __restrict__ W2,
                        const float* __restrict__ b2, unsigned short* __restrict__ Aw) {
    __shared__ float hs[16*256];
    __shared__ float red[4][16][65];
    int t = threadIdx.x;
    for (int i = t; i < 16*256; i += 256) hs[i] = h[i];
    __syncthreads();

    int nl = t & 63;
    int kc = t >> 6;                 // 0..3
    int n  = blockIdx.x * 64 + nl;
    float acc[16] = {};
    #pragma unroll
    for (int kk = 0; kk < 64; ++kk) {
        int k = kc*64 + kk;
        float w = W2[(size_t)k*NW2 + n];
        #pragma unroll
        for (int b = 0; b < 16; ++b) acc[b] += hs[b*256 + k] * w;
    }
    #pragma unroll
    for (int b = 0; b < 16; ++b) red[kc][b][nl] = acc[b];
    __syncthreads();

    for (int i = t; i < 16*64; i += 256) {
        int b  = i >> 6;
        int nn = i & 63;
        int n2 = blockIdx.x * 64 + nn;
        float s = red[0][b][nn] + red[1][b][nn] + red[2][b][nn] + red[3][b][nn] + b2[n2];
        // n2 = co*576 + ci*9 + tap   (reshape order COUT,CIN,3,3)
        int co  = n2 / 576;
        int rem = n2 - co*576;
        int ci  = rem / 9;
        int tap = rem - ci*9;
        Aw[(((b*9 + tap)*COUT + co)*CIN) + ci] = f2bf(s);
    }
}

// ---------------- k3: xT[b][p][ci] bf16 = x[b][ci][p] ----------------
__global__ void k3_transpose(const float* __restrict__ x, unsigned short* __restrict__ xT) {
    __shared__ float tile[64][65];
    int b  = blockIdx.y;
    int p0 = blockIdx.x * 64;
    int t  = threadIdx.x;
    const float* xb = x + (size_t)b * CIN * NPIX;
    {
        int c  = (t & 15) * 4;   // p within tile
        int r0 = t >> 4;         // 0..15
        #pragma unroll
        for (int i = 0; i < 4; ++i) {
            int ci = r0 + 16*i;
            float4 v = *(const float4*)(xb + (size_t)ci*NPIX + p0 + c);
            tile[ci][c] = v.x; tile[ci][c+1] = v.y; tile[ci][c+2] = v.z; tile[ci][c+3] = v.w;
        }
    }
    __syncthreads();
    {
        int ci4 = (t & 15) * 4;
        int pr  = t >> 4;        // 0..15
        #pragma unroll
        for (int i = 0; i < 4; ++i) {
            int pl = pr + 16*i;
            uint2 w;
            w.x = (unsigned int)f2bf(tile[ci4  ][pl]) | ((unsigned int)f2bf(tile[ci4+1][pl]) << 16);
            w.y = (unsigned int)f2bf(tile[ci4+2][pl]) | ((unsigned int)f2bf(tile[ci4+3][pl]) << 16);
            *(uint2*)(&xT[((size_t)b*NPIX + p0 + pl)*CIN + ci4]) = w;
        }
    }
}

// ---------------- k4: MFMA conv ----------------
// 1-D grid 2304 (= 6x * 24y * 16b), block 256 (4 waves). Tile: 64co x (8y x 32x).
// LDS xs: slot s (16B) holds pixel t=s>>3, chunk swc=s&7, where the SOURCE chunk is
// c = swc ^ (gx&7)  (pre-swizzled global source, linear LDS dest -> global_load_lds OK).
// A-fragments double-buffered in registers (prefetch tap+1 during tap's MFMAs).
#define XS_SLOTS 2816   // ceil(10*34*8 / 256)*256
__global__ __launch_bounds__(256, 3)
void k4_conv(const unsigned short* __restrict__ xT, const unsigned short* __restrict__ Aw,
             float* __restrict__ out) {
    __shared__ unsigned short xs[XS_SLOTS*8];   // 45056 B
    const int tid = threadIdx.x;

    // bijective XCD swizzle: 2304 % 8 == 0, 288 consecutive tiles per XCD
    int bid = blockIdx.x;
    int wg  = (bid & 7) * 288 + (bid >> 3);
    int b   = wg / 144;
    int ry  = wg - b*144;
    int ty  = ry / 6;
    int tx  = ry - ty*6;
    const int x0 = tx * 32;
    const int y0 = ty * 8;

    const int wv  = tid >> 6;    // wave 0..3 -> rows 2w,2w+1
    const int l   = tid & 63;
    const int l15 = l & 15;
    const int lg  = l >> 4;      // 0..3

    // ---- stage input tile via global_load_lds (pre-swizzled source) ----
    const unsigned short* xTb = xT + (size_t)b * NPIX * CIN;
    #pragma unroll
    for (int it = 0; it < 11; ++it) {
        int s   = it*256 + tid;
        int t   = s >> 3;
        int swc = s & 7;
        int gyl = t / 34;
        int gxl = t - gyl*34;
        int gy  = y0 + gyl; gy = gy > 191 ? 191 : gy;
        int gx  = x0 + gxl; gx = gx > 191 ? 191 : gx;
        const void* src = xTb + ((size_t)(gy*HW + gx))*CIN + ((swc ^ (gx & 7)) * 8);
        void* dst = &xs[(it*256 + wv*64) * 8];
        async_copy16(src, dst);
    }

    // ---- prefetch A for tap 0 while staging drains ----
    const unsigned short* Ab = Aw + b * (9*COUT*CIN);
    const unsigned short* Al = Ab + l15*CIN + lg*8;   // lane base
    bf16x8 a[2][8];   // [buf][cc*4+m]
    #pragma unroll
    for (int cc = 0; cc < 2; ++cc)
        #pragma unroll
        for (int m = 0; m < 4; ++m)
            a[0][cc*4+m] = *(const bf16x8*)(Al + m*1024 + cc*32);

    __syncthreads();   // drains vmcnt(0) -> xs + a[0] ready

    f32x4 acc[4][4] = {};        // [m co-group][n = r*2+xb]

    #pragma unroll
    for (int tap = 0; tap < 9; ++tap) {
        const int cur = tap & 1, nxt = cur ^ 1;
        if (tap < 8) {
            #pragma unroll
            for (int cc = 0; cc < 2; ++cc)
                #pragma unroll
                for (int m = 0; m < 4; ++m)
                    a[nxt][cc*4+m] = *(const bf16x8*)(Al + (tap+1)*4096 + m*1024 + cc*32);
        }
        const int ky = tap / 3, kx = tap - 3*(tap/3);
        #pragma unroll
        for (int cc = 0; cc < 2; ++cc) {
            bf16x8 bb[4];
            #pragma unroll
            for (int r = 0; r < 2; ++r)
                #pragma unroll
                for (int xb = 0; xb < 2; ++xb) {
                    int gyl = 2*wv + r + ky;
                    int gxl = xb*16 + l15 + kx;
                    int pch = (cc*4 + lg) ^ (gxl & 7);
                    bb[r*2 + xb] = *(const bf16x8*)(&xs[((gyl*34 + gxl)*8 + pch)*8]);
                }
            #pragma unroll
            for (int m = 0; m < 4; ++m)
                #pragma unroll
                for (int n = 0; n < 4; ++n)
                    acc[m][n] = __builtin_amdgcn_mfma_f32_16x16x32_bf16(a[cur][cc*4+m], bb[n], acc[m][n], 0, 0, 0);
        }
    }

    // ---- epilogue: D col = lane&15 (spatial), row = (lane>>4)*4+j (co) ----
    #pragma unroll
    for (int m = 0; m < 4; ++m)
        #pragma unroll
        for (int r = 0; r < 2; ++r)
            #pragma unroll
            for (int xb = 0; xb < 2; ++xb) {
                int oy = y0 + 2*wv + r;
                int ox = x0 + xb*16 + l15;
                if (oy < OHW && ox < OHW) {
                    f32x4 v = acc[m][r*2 + xb];
                    #pragma unroll
                    for (int j = 0; j < 4; ++j) {
                        int co = m*16 + lg*4 + j;
                        out[(((size_t)(b*COUT + co)*OHW + oy)*OHW) + ox] = v[j];
                    }
                }
            }
}

// ---------------- fallback: naive direct conv (if ws too small for xT) ----------------
__global__ void k4_naive(const float* __restrict__ x, const unsigned short* __restrict__ Aw,
                         float* __restrict__ out) {
    int p = blockIdx.x * 256 + threadIdx.x;
    if (p >= OHW*OHW) return;
    int b = blockIdx.z, co = blockIdx.y;
    int oy = p / OHW, ox = p - oy*OHW;
    const float* xb = x + (size_t)b * CIN * NPIX;
    float acc = 0.f;
    for (int ci = 0; ci < CIN; ++ci)
        for (int ky = 0; ky < 3; ++ky) {
            const float* row = xb + ci*NPIX + (oy + ky)*HW + ox;
            #pragma unroll
            for (int kx = 0; kx < 3; ++kx) {
                float w = bf2f(Aw[(((b*9 + ky*3 + kx)*COUT + co)*CIN) + ci]);
                acc += row[kx] * w;
            }
        }
    out[(((b*COUT + co)*OHW + oy)*OHW) + ox] = acc;
}

extern "C" void kernel_launch(void* const* d_in, const int* in_sizes, int n_in,
                              void* d_out, int out_size, void* d_ws, size_t ws_size,
                              hipStream_t stream) {
    const float* x   = (const float*)d_in[0];
    const float* deg = (const float*)d_in[1];
    const float* W1  = (const float*)d_in[2];
    const float* b1  = (const float*)d_in[3];
    const float* W2  = (const float*)d_in[4];
    const float* b2  = (const float*)d_in[5];
    float* out = (float*)d_out;

    const size_t off_h  = 0;                       // 16 KB
    const size_t off_Aw = 16 * 1024;
    const size_t off_xT = off_Aw + (size_t)NB*9*COUT*CIN*2;   // 16B aligned
    const size_t need   = off_xT + (size_t)NB*NPIX*CIN*2;     // ~76.7 MB

    float* h           = (float*)((char*)d_ws + off_h);
    unsigned short* Aw = (unsigned short*)((char*)d_ws + off_Aw);

    k1_hidden<<<16, 256, 0, stream>>>(deg, W1, b1, h);
    k2_wgen<<<NW2/64, 256, 0, stream>>>(h, W2, b2, Aw);

    if (ws_size >= need) {
        unsigned short* xT = (unsigned short*)((char*)d_ws + off_xT);
        k3_transpose<<<dim3(NPIX/64, NB), 256, 0, stream>>>(x, xT);
        k4_conv<<<2304, 256, 0, stream>>>(xT, Aw, out);
    } else {
        k4_naive<<<dim3((OHW*OHW + 255)/256, COUT, NB), 256, 0, stream>>>(x, Aw, out);
    }
}